// Round 1
// baseline (427.160 us; speedup 1.0000x reference)
//
#include <hip/hip_runtime.h>
#include <hip/hip_bf16.h>
#include <stdint.h>

#define EE 131072
#define NN 100000
#define DDEG 64
#define HH 256

typedef __bf16 bf16_t;
typedef bf16_t bf16x8 __attribute__((ext_vector_type(8)));
typedef float floatx4 __attribute__((ext_vector_type(4)));

// ---------------- CN pair-count: one wave per edge ----------------
__global__ __launch_bounds__(256)
void cn_kernel(const int* __restrict__ nbr, const int* __restrict__ tar,
               int* __restrict__ xcn, int* __restrict__ flags) {
    int wid  = (blockIdx.x * blockDim.x + threadIdx.x) >> 6;
    int lane = threadIdx.x & 63;
    if (wid >= EE) return;
    int s = tar[wid];
    int d = tar[EE + wid];
    int a = nbr[(size_t)s * DDEG + lane];
    int b = nbr[(size_t)d * DDEG + lane];
    int cnt = 0;
    #pragma unroll
    for (int k = 0; k < 64; ++k) {
        int bk = __shfl(b, k, 64);
        cnt += (a == bk) ? 1 : 0;
    }
    #pragma unroll
    for (int off = 32; off > 0; off >>= 1)
        cnt += __shfl_xor(cnt, off, 64);
    if (lane == 0) {
        xcn[wid] = cnt;
        flags[cnt] = 1;   // benign race, same value
    }
}

// ---------------- CN-MLP table for occurring values only ----------------
__global__ __launch_bounds__(256)
void table_kernel(const float* __restrict__ w1, const float* __restrict__ b1,
                  const float* __restrict__ w2, const float* __restrict__ b2,
                  const float* __restrict__ w3, const float* __restrict__ b3,
                  const float* __restrict__ beta, const int* __restrict__ flags,
                  float* __restrict__ T) {
    int v = blockIdx.x;
    if (flags[v] == 0) return;    // uniform branch, before any barrier
    int h = threadIdx.x;
    __shared__ float t1[256];
    __shared__ float t2[256];
    float fv = (float)v;
    t1[h] = fmaxf(fv * w1[h] + b1[h], 0.f);
    __syncthreads();
    float s = b2[h];
    for (int k = 0; k < 256; ++k) s += t1[k] * w2[k * 256 + h];
    t2[h] = fmaxf(s, 0.f);
    __syncthreads();
    s = b3[h];
    for (int k = 0; k < 256; ++k) s += t2[k] * w3[k * 256 + h];
    T[v * 256 + h] = s * beta[0];   // beta folded into table
}

// ---------------- weight transpose fp32[k][n] -> bf16[n][k] ----------------
__global__ __launch_bounds__(256)
void transpose_w(const float* __restrict__ W, bf16_t* __restrict__ Wt) {
    __shared__ float tile[32][33];
    int bx = blockIdx.x & 7;
    int by = blockIdx.x >> 3;
    int tx = threadIdx.x & 31;
    int ty = threadIdx.x >> 5;   // 0..7
    #pragma unroll
    for (int r = 0; r < 32; r += 8)
        tile[ty + r][tx] = W[(by * 32 + ty + r) * 256 + bx * 32 + tx];
    __syncthreads();
    #pragma unroll
    for (int r = 0; r < 32; r += 8)
        Wt[(bx * 32 + ty + r) * 256 + by * 32 + tx] = (bf16_t)tile[tx][ty + r];
}

// ---------------- fused MFMA GEMM: [E,256] x [256,256] ----------------
// MODE 1: A = xi*xj (gathered fp32), epi: +b, relu, store bf16 g
// MODE 2: A = g,                     epi: +b,       store bf16 xij (in place)
// MODE 3: A = xij + T[xcn] (staged), epi: +b, relu, dot lin_w2, +lin_b2 -> out
template<int MODE>
__global__ __launch_bounds__(512)
void gemm_kernel(const float* __restrict__ x, const int* __restrict__ tar,
                 const bf16_t* Ain, const bf16_t* __restrict__ Wt,
                 const float* __restrict__ bias, const float* __restrict__ T,
                 const int* __restrict__ xcn, const float* __restrict__ w2,
                 const float* __restrict__ b2s,
                 bf16_t* Aout, float* __restrict__ out) {
    __shared__ bf16_t lA[128 * 40];   // 128 rows x 32 k, pitch 40 (pad 8)
    __shared__ bf16_t lB[256 * 40];   // 256 n    x 32 k, pitch 40
    __shared__ float rowacc[128];

    const int tid  = threadIdx.x;
    const int lane = tid & 63;
    const int w    = tid >> 6;
    const int wr   = w >> 2;          // 0..1  (row half)
    const int wc   = w & 3;           // 0..3  (col quarter)
    const int quad = lane >> 4;
    const int l16  = lane & 15;
    const int e0   = blockIdx.x * 128;

    if (MODE == 3 && tid < 128) rowacc[tid] = 0.f;

    floatx4 acc[4][4];
    #pragma unroll
    for (int i = 0; i < 4; ++i)
        #pragma unroll
        for (int j = 0; j < 4; ++j)
            acc[i][j] = (floatx4){0.f, 0.f, 0.f, 0.f};

    const int srow  = tid >> 2;        // 0..127, 4 threads per A row
    const int skoff = (tid & 3) * 8;   // element offset within 32-chunk
    const int brow  = tid >> 1;        // 0..255, 2 threads per B row
    const int bkoff = (tid & 1) * 16;

    const float*  xi   = nullptr;
    const float*  xj   = nullptr;
    const bf16_t* arow = nullptr;
    const float*  trow = nullptr;
    if (MODE == 1) {
        int e  = e0 + srow;
        int si = tar[e];
        int di = tar[EE + e];
        xi = x + (size_t)si * 256;
        xj = x + (size_t)di * 256;
    } else {
        arow = Ain + (size_t)(e0 + srow) * 256;
        if (MODE == 3) trow = T + (size_t)xcn[e0 + srow] * 256;
    }
    const bf16_t* wrow = Wt + (size_t)brow * 256;

    #pragma unroll 1
    for (int kc = 0; kc < 8; ++kc) {
        const int k0 = kc * 32;
        bf16_t* da = &lA[srow * 40 + skoff];
        if (MODE == 1) {
            float4 a0 = *(const float4*)(xi + k0 + skoff);
            float4 a1 = *(const float4*)(xi + k0 + skoff + 4);
            float4 c0 = *(const float4*)(xj + k0 + skoff);
            float4 c1 = *(const float4*)(xj + k0 + skoff + 4);
            bf16x8 v;
            v[0] = (bf16_t)(a0.x * c0.x); v[1] = (bf16_t)(a0.y * c0.y);
            v[2] = (bf16_t)(a0.z * c0.z); v[3] = (bf16_t)(a0.w * c0.w);
            v[4] = (bf16_t)(a1.x * c1.x); v[5] = (bf16_t)(a1.y * c1.y);
            v[6] = (bf16_t)(a1.z * c1.z); v[7] = (bf16_t)(a1.w * c1.w);
            *(bf16x8*)da = v;
        } else if (MODE == 2) {
            *(bf16x8*)da = *(const bf16x8*)(arow + k0 + skoff);
        } else {
            bf16x8 v = *(const bf16x8*)(arow + k0 + skoff);
            float4 t0 = *(const float4*)(trow + k0 + skoff);
            float4 t1 = *(const float4*)(trow + k0 + skoff + 4);
            bf16x8 o;
            o[0] = (bf16_t)((float)v[0] + t0.x); o[1] = (bf16_t)((float)v[1] + t0.y);
            o[2] = (bf16_t)((float)v[2] + t0.z); o[3] = (bf16_t)((float)v[3] + t0.w);
            o[4] = (bf16_t)((float)v[4] + t1.x); o[5] = (bf16_t)((float)v[5] + t1.y);
            o[6] = (bf16_t)((float)v[6] + t1.z); o[7] = (bf16_t)((float)v[7] + t1.w);
            *(bf16x8*)da = o;
        }
        {
            bf16_t* db = &lB[brow * 40 + bkoff];
            *(bf16x8*)(db)     = *(const bf16x8*)(wrow + k0 + bkoff);
            *(bf16x8*)(db + 8) = *(const bf16x8*)(wrow + k0 + bkoff + 8);
        }
        __syncthreads();

        bf16x8 af[4], bfr[4];
        const bf16_t* pa = &lA[(wr * 64 + l16) * 40 + quad * 8];
        const bf16_t* pb = &lB[(wc * 64 + l16) * 40 + quad * 8];
        #pragma unroll
        for (int i = 0; i < 4; ++i) af[i]  = *(const bf16x8*)(pa + i * 16 * 40);
        #pragma unroll
        for (int j = 0; j < 4; ++j) bfr[j] = *(const bf16x8*)(pb + j * 16 * 40);
        #pragma unroll
        for (int i = 0; i < 4; ++i)
            #pragma unroll
            for (int j = 0; j < 4; ++j)
                acc[i][j] = __builtin_amdgcn_mfma_f32_16x16x32_bf16(
                                af[i], bfr[j], acc[i][j], 0, 0, 0);
        __syncthreads();
    }

    if (MODE == 1 || MODE == 2) {
        #pragma unroll
        for (int j = 0; j < 4; ++j) {
            int col  = wc * 64 + j * 16 + l16;
            float bv = bias[col];
            #pragma unroll
            for (int i = 0; i < 4; ++i) {
                int row = wr * 64 + i * 16 + quad * 4;
                #pragma unroll
                for (int r = 0; r < 4; ++r) {
                    float v = acc[i][j][r] + bv;
                    if (MODE == 1) v = fmaxf(v, 0.f);
                    Aout[(size_t)(e0 + row + r) * 256 + col] = (bf16_t)v;
                }
            }
        }
    } else {
        float lb2v = b2s[0];
        float pr[16];
        #pragma unroll
        for (int t = 0; t < 16; ++t) pr[t] = 0.f;
        #pragma unroll
        for (int j = 0; j < 4; ++j) {
            int col  = wc * 64 + j * 16 + l16;
            float bv = bias[col];
            float wv = w2[col];
            #pragma unroll
            for (int i = 0; i < 4; ++i)
                #pragma unroll
                for (int r = 0; r < 4; ++r) {
                    float v = fmaxf(acc[i][j][r] + bv, 0.f);
                    pr[i * 4 + r] += v * wv;
                }
        }
        #pragma unroll
        for (int off = 1; off < 16; off <<= 1)
            #pragma unroll
            for (int t = 0; t < 16; ++t)
                pr[t] += __shfl_xor(pr[t], off, 64);
        if (l16 == 0) {
            #pragma unroll
            for (int i = 0; i < 4; ++i)
                #pragma unroll
                for (int r = 0; r < 4; ++r)
                    atomicAdd(&rowacc[wr * 64 + i * 16 + quad * 4 + r],
                              pr[i * 4 + r]);
        }
        __syncthreads();
        if (tid < 128) out[e0 + tid] = rowacc[tid] + lb2v;
    }
}

extern "C" void kernel_launch(void* const* d_in, const int* in_sizes, int n_in,
                              void* d_out, int out_size, void* d_ws, size_t ws_size,
                              hipStream_t stream) {
    const float* x      = (const float*)d_in[0];
    const int*   nbr    = (const int*)  d_in[1];
    const int*   tar    = (const int*)  d_in[2];
    const float* beta   = (const float*)d_in[3];
    const float* cn_w1  = (const float*)d_in[4];
    const float* cn_b1  = (const float*)d_in[5];
    const float* cn_w2  = (const float*)d_in[6];
    const float* cn_b2  = (const float*)d_in[7];
    const float* cn_w3  = (const float*)d_in[8];
    const float* cn_b3  = (const float*)d_in[9];
    const float* ij_w1  = (const float*)d_in[10];
    const float* ij_b1  = (const float*)d_in[11];
    const float* ij_w2  = (const float*)d_in[12];
    const float* ij_b2  = (const float*)d_in[13];
    const float* lin_w1 = (const float*)d_in[14];
    const float* lin_b1 = (const float*)d_in[15];
    const float* lin_w2 = (const float*)d_in[16];
    const float* lin_b2 = (const float*)d_in[17];

    char* ws = (char*)d_ws;
    float*  T     = (float*) (ws + 0);         // 4097*256*4 = 4,195,328
    int*    flags = (int*)   (ws + 4195328);   // 4097*4
    int*    xcn   = (int*)   (ws + 4212224);   // E*4 = 524,288
    bf16_t* Wt1   = (bf16_t*)(ws + 4736512);   // 256*256*2
    bf16_t* Wt2   = (bf16_t*)(ws + 4867584);
    bf16_t* Wt3   = (bf16_t*)(ws + 4998656);
    bf16_t* g     = (bf16_t*)(ws + 5129728);   // E*256*2 = 67,108,864 (g, then xij in place)

    hipMemsetAsync(flags, 0, 4097 * sizeof(int), stream);

    cn_kernel<<<EE / 4, 256, 0, stream>>>(nbr, tar, xcn, flags);
    table_kernel<<<4097, 256, 0, stream>>>(cn_w1, cn_b1, cn_w2, cn_b2,
                                           cn_w3, cn_b3, beta, flags, T);
    transpose_w<<<64, 256, 0, stream>>>(ij_w1, Wt1);
    transpose_w<<<64, 256, 0, stream>>>(ij_w2, Wt2);
    transpose_w<<<64, 256, 0, stream>>>(lin_w1, Wt3);

    gemm_kernel<1><<<EE / 128, 512, 0, stream>>>(x, tar, nullptr, Wt1, ij_b1,
                                                 nullptr, nullptr, nullptr, nullptr,
                                                 g, nullptr);
    gemm_kernel<2><<<EE / 128, 512, 0, stream>>>(nullptr, nullptr, g, Wt2, ij_b2,
                                                 nullptr, nullptr, nullptr, nullptr,
                                                 g, nullptr);
    gemm_kernel<3><<<EE / 128, 512, 0, stream>>>(nullptr, nullptr, g, Wt3, lin_b1,
                                                 T, xcn, lin_w2, lin_b2,
                                                 nullptr, (float*)d_out);
}

// Round 2
// 422.404 us; speedup vs baseline: 1.0113x; 1.0113x over previous
//
#include <hip/hip_runtime.h>
#include <hip/hip_bf16.h>
#include <stdint.h>

#define EE 131072
#define DDEG 64

typedef __bf16 bf16_t;
typedef bf16_t bf16x8 __attribute__((ext_vector_type(8)));
typedef float floatx4 __attribute__((ext_vector_type(4)));

// ---------------- CN pair-count: one wave per edge, scalar b-row ----------------
// b-row is wave-uniform -> s_load; count via v_cmp + ballot popcount (scalar pipe).
__global__ __launch_bounds__(256)
void cn_kernel(const int* __restrict__ nbr, const int* __restrict__ tar,
               int* __restrict__ xcn, int* __restrict__ flags) {
    int wid  = (blockIdx.x * 256 + threadIdx.x) >> 6;
    int lane = threadIdx.x & 63;
    int s = __builtin_amdgcn_readfirstlane(tar[wid]);
    int d = __builtin_amdgcn_readfirstlane(tar[EE + wid]);
    int a = nbr[(size_t)s * DDEG + lane];                 // coalesced 256B row
    const int* __restrict__ brow = nbr + (size_t)d * DDEG; // uniform -> s_load
    int cnt = 0;
    #pragma unroll
    for (int k = 0; k < 64; ++k) {
        int bk = brow[k];
        cnt += __builtin_popcountll(__ballot(a == bk));
    }
    if (lane == 0) { xcn[wid] = cnt; flags[cnt] = 1; }
}

// ---------------- CN-MLP table folded through lin_w1: T2[v] = (MLP(v)*beta)@lin_w1
__global__ __launch_bounds__(256)
void table_kernel(const float* __restrict__ w1, const float* __restrict__ b1,
                  const float* __restrict__ w2, const float* __restrict__ b2,
                  const float* __restrict__ w3, const float* __restrict__ b3,
                  const float* __restrict__ beta, const float* __restrict__ lw1,
                  const int* __restrict__ flags, float* __restrict__ T2) {
    int v = blockIdx.x;
    if (flags[v] == 0) return;    // uniform, before any barrier
    int h = threadIdx.x;
    __shared__ float t1[256];
    __shared__ float t2[256];
    __shared__ float t3[256];
    float fv = (float)v;
    t1[h] = fmaxf(fv * w1[h] + b1[h], 0.f);
    __syncthreads();
    float s = b2[h];
    for (int k = 0; k < 256; ++k) s += t1[k] * w2[k * 256 + h];
    t2[h] = fmaxf(s, 0.f);
    __syncthreads();
    s = b3[h];
    for (int k = 0; k < 256; ++k) s += t2[k] * w3[k * 256 + h];
    t3[h] = s * beta[0];
    __syncthreads();
    s = 0.f;
    for (int k = 0; k < 256; ++k) s += t3[k] * lw1[k * 256 + h];
    T2[(size_t)v * 256 + h] = s;
}

// ---------------- weight transpose fp32[k][n] -> bf16[n][k] ----------------
__global__ __launch_bounds__(256)
void transpose_w(const float* __restrict__ W, bf16_t* __restrict__ Wt) {
    __shared__ float tile[32][33];
    int bx = blockIdx.x & 7;
    int by = blockIdx.x >> 3;
    int tx = threadIdx.x & 31;
    int ty = threadIdx.x >> 5;
    #pragma unroll
    for (int r = 0; r < 32; r += 8)
        tile[ty + r][tx] = W[(by * 32 + ty + r) * 256 + bx * 32 + tx];
    __syncthreads();
    #pragma unroll
    for (int r = 0; r < 32; r += 8)
        Wt[(bx * 32 + ty + r) * 256 + by * 32 + tx] = (bf16_t)tile[tx][ty + r];
}

// ---------------- Mt[b][a] = sum_c ij_w2[a][c] * lin_w1[c][b]  (bf16, [n][k]) --
__global__ __launch_bounds__(256)
void mt_kernel(const float* __restrict__ w2, const float* __restrict__ lw1,
               bf16_t* __restrict__ Mt) {
    __shared__ float S[256][33];
    int b = blockIdx.x, t = threadIdx.x;
    int cc = t & 31, abase = t >> 5;
    float acc = 0.f;
    for (int c0 = 0; c0 < 256; c0 += 32) {
        __syncthreads();
        #pragma unroll
        for (int r = 0; r < 32; ++r) {
            int a = r * 8 + abase;
            S[a][cc] = w2[a * 256 + c0 + cc];
        }
        __syncthreads();
        #pragma unroll 8
        for (int c2 = 0; c2 < 32; ++c2) {
            float wv = lw1[(c0 + c2) * 256 + b];   // uniform -> scalar
            acc += S[t][c2] * wv;
        }
    }
    Mt[(size_t)b * 256 + t] = (bf16_t)acc;
}

// ---------------- cvec[b] = ij_b2 @ lin_w1 + lin_b1 ----------------
__global__ __launch_bounds__(256)
void cvec_kernel(const float* __restrict__ b2, const float* __restrict__ lw1,
                 const float* __restrict__ lb1, float* __restrict__ cvec) {
    int b = threadIdx.x;
    float s = lb1[b];
    for (int c = 0; c < 256; ++c) s += b2[c] * lw1[c * 256 + b];
    cvec[b] = s;
}

// ---------------- fused: g=relu((xi*xj)@W1+b1); z=relu(g@M + cvec + T2[xcn]);
//                  out = z@lin_w2 + lin_b2.   64 rows/block, 256 threads. ------
__global__ __launch_bounds__(256, 2)
void fused_kernel(const float* __restrict__ x, const int* __restrict__ tar,
                  const bf16_t* __restrict__ Wt1, const float* __restrict__ b1,
                  const bf16_t* __restrict__ Mt, const float* __restrict__ cvec,
                  const float* __restrict__ T2, const int* __restrict__ xcn,
                  const float* __restrict__ w2, const float* __restrict__ b2s,
                  float* __restrict__ out) {
    __shared__ __align__(16) bf16_t lA[64 * 40];    // 64 rows x 32k, pitch 40
    __shared__ __align__(16) bf16_t lB[256 * 40];   // 256 n x 32k, pitch 40
    __shared__ __align__(16) bf16_t gt[64 * 264];   // g tile, pitch 264
    __shared__ float rowacc[64];

    const int tid  = threadIdx.x;
    const int lane = tid & 63;
    const int wc   = tid >> 6;          // wave = col quarter 0..3
    const int quad = lane >> 4;
    const int l16  = lane & 15;
    const int e0   = blockIdx.x * 64;

    if (tid < 64) rowacc[tid] = 0.f;

    floatx4 acc[4][4];
    #pragma unroll
    for (int i = 0; i < 4; ++i)
        #pragma unroll
        for (int j = 0; j < 4; ++j)
            acc[i][j] = (floatx4){0.f, 0.f, 0.f, 0.f};

    const int srow  = tid >> 2;          // 0..63, 4 thr/row
    const int skoff = (tid & 3) * 8;
    const int brow  = tid;               // 0..255, 1 thr/row, 32 el

    int e = e0 + srow;
    const float* xi = x + (size_t)tar[e] * 256;
    const float* xj = x + (size_t)tar[EE + e] * 256;
    const bf16_t* w1row = Wt1 + (size_t)brow * 256;

    // ---- GEMM1: (xi*xj) @ W1 ----
    #pragma unroll 1
    for (int kc = 0; kc < 8; ++kc) {
        const int k0 = kc * 32;
        {
            float4 a0 = *(const float4*)(xi + k0 + skoff);
            float4 a1 = *(const float4*)(xi + k0 + skoff + 4);
            float4 c0 = *(const float4*)(xj + k0 + skoff);
            float4 c1 = *(const float4*)(xj + k0 + skoff + 4);
            bf16x8 v;
            v[0] = (bf16_t)(a0.x * c0.x); v[1] = (bf16_t)(a0.y * c0.y);
            v[2] = (bf16_t)(a0.z * c0.z); v[3] = (bf16_t)(a0.w * c0.w);
            v[4] = (bf16_t)(a1.x * c1.x); v[5] = (bf16_t)(a1.y * c1.y);
            v[6] = (bf16_t)(a1.z * c1.z); v[7] = (bf16_t)(a1.w * c1.w);
            *(bf16x8*)&lA[srow * 40 + skoff] = v;
        }
        {
            bf16_t* db = &lB[brow * 40];
            *(bf16x8*)(db)      = *(const bf16x8*)(w1row + k0);
            *(bf16x8*)(db + 8)  = *(const bf16x8*)(w1row + k0 + 8);
            *(bf16x8*)(db + 16) = *(const bf16x8*)(w1row + k0 + 16);
            *(bf16x8*)(db + 24) = *(const bf16x8*)(w1row + k0 + 24);
        }
        __syncthreads();
        bf16x8 af[4], bfr[4];
        const bf16_t* pa = &lA[l16 * 40 + quad * 8];
        const bf16_t* pb = &lB[(wc * 64 + l16) * 40 + quad * 8];
        #pragma unroll
        for (int i = 0; i < 4; ++i) af[i]  = *(const bf16x8*)(pa + i * 16 * 40);
        #pragma unroll
        for (int j = 0; j < 4; ++j) bfr[j] = *(const bf16x8*)(pb + j * 16 * 40);
        #pragma unroll
        for (int i = 0; i < 4; ++i)
            #pragma unroll
            for (int j = 0; j < 4; ++j)
                acc[i][j] = __builtin_amdgcn_mfma_f32_16x16x32_bf16(
                                af[i], bfr[j], acc[i][j], 0, 0, 0);
        __syncthreads();
    }

    // ---- epilogue 1: g tile -> LDS (bf16) ----
    #pragma unroll
    for (int j = 0; j < 4; ++j) {
        int col  = wc * 64 + j * 16 + l16;
        float bv = b1[col];
        #pragma unroll
        for (int i = 0; i < 4; ++i)
            #pragma unroll
            for (int r = 0; r < 4; ++r) {
                int row = i * 16 + quad * 4 + r;
                gt[row * 264 + col] = (bf16_t)fmaxf(acc[i][j][r] + bv, 0.f);
            }
    }
    #pragma unroll
    for (int i = 0; i < 4; ++i)
        #pragma unroll
        for (int j = 0; j < 4; ++j)
            acc[i][j] = (floatx4){0.f, 0.f, 0.f, 0.f};
    __syncthreads();

    // ---- GEMM2': g @ M ----
    const bf16_t* mrow = Mt + (size_t)brow * 256;
    #pragma unroll 1
    for (int kc = 0; kc < 8; ++kc) {
        const int k0 = kc * 32;
        {
            bf16_t* db = &lB[brow * 40];
            *(bf16x8*)(db)      = *(const bf16x8*)(mrow + k0);
            *(bf16x8*)(db + 8)  = *(const bf16x8*)(mrow + k0 + 8);
            *(bf16x8*)(db + 16) = *(const bf16x8*)(mrow + k0 + 16);
            *(bf16x8*)(db + 24) = *(const bf16x8*)(mrow + k0 + 24);
        }
        __syncthreads();
        bf16x8 af[4], bfr[4];
        const bf16_t* pa = &gt[l16 * 264 + k0 + quad * 8];
        const bf16_t* pb = &lB[(wc * 64 + l16) * 40 + quad * 8];
        #pragma unroll
        for (int i = 0; i < 4; ++i) af[i]  = *(const bf16x8*)(pa + i * 16 * 264);
        #pragma unroll
        for (int j = 0; j < 4; ++j) bfr[j] = *(const bf16x8*)(pb + j * 16 * 40);
        #pragma unroll
        for (int i = 0; i < 4; ++i)
            #pragma unroll
            for (int j = 0; j < 4; ++j)
                acc[i][j] = __builtin_amdgcn_mfma_f32_16x16x32_bf16(
                                af[i], bfr[j], acc[i][j], 0, 0, 0);
        __syncthreads();
    }

    // ---- final epilogue: +cvec +T2[xcn], relu, dot lin_w2, row-reduce ----
    int xv[16];
    #pragma unroll
    for (int i = 0; i < 4; ++i)
        #pragma unroll
        for (int r = 0; r < 4; ++r)
            xv[i * 4 + r] = xcn[e0 + i * 16 + quad * 4 + r];

    float pr[16];
    #pragma unroll
    for (int t = 0; t < 16; ++t) pr[t] = 0.f;
    #pragma unroll
    for (int j = 0; j < 4; ++j) {
        int col  = wc * 64 + j * 16 + l16;
        float cv = cvec[col];
        float wv = w2[col];
        #pragma unroll
        for (int i = 0; i < 4; ++i)
            #pragma unroll
            for (int r = 0; r < 4; ++r) {
                float t2v = T2[(size_t)xv[i * 4 + r] * 256 + col];
                float v = fmaxf(acc[i][j][r] + cv + t2v, 0.f);
                pr[i * 4 + r] += v * wv;
            }
    }
    #pragma unroll
    for (int off = 1; off < 16; off <<= 1)
        #pragma unroll
        for (int t = 0; t < 16; ++t)
            pr[t] += __shfl_xor(pr[t], off, 64);
    if (l16 == 0) {
        #pragma unroll
        for (int i = 0; i < 4; ++i)
            #pragma unroll
            for (int r = 0; r < 4; ++r)
                atomicAdd(&rowacc[i * 16 + quad * 4 + r], pr[i * 4 + r]);
    }
    __syncthreads();
    if (tid < 64) out[e0 + tid] = rowacc[tid] + b2s[0];
}

extern "C" void kernel_launch(void* const* d_in, const int* in_sizes, int n_in,
                              void* d_out, int out_size, void* d_ws, size_t ws_size,
                              hipStream_t stream) {
    const float* x      = (const float*)d_in[0];
    const int*   nbr    = (const int*)  d_in[1];
    const int*   tar    = (const int*)  d_in[2];
    const float* beta   = (const float*)d_in[3];
    const float* cn_w1  = (const float*)d_in[4];
    const float* cn_b1  = (const float*)d_in[5];
    const float* cn_w2  = (const float*)d_in[6];
    const float* cn_b2  = (const float*)d_in[7];
    const float* cn_w3  = (const float*)d_in[8];
    const float* cn_b3  = (const float*)d_in[9];
    const float* ij_w1  = (const float*)d_in[10];
    const float* ij_b1  = (const float*)d_in[11];
    const float* ij_w2  = (const float*)d_in[12];
    const float* ij_b2  = (const float*)d_in[13];
    const float* lin_w1 = (const float*)d_in[14];
    const float* lin_b1 = (const float*)d_in[15];
    const float* lin_w2 = (const float*)d_in[16];
    const float* lin_b2 = (const float*)d_in[17];

    char* ws = (char*)d_ws;
    float*  T2    = (float*) (ws + 0);         // 4097*256*4 = 4,195,328
    int*    flags = (int*)   (ws + 4195328);   // 4097*4
    int*    xcn   = (int*)   (ws + 4212224);   // E*4
    bf16_t* Wt1   = (bf16_t*)(ws + 4736512);   // 256*256*2
    bf16_t* Mt    = (bf16_t*)(ws + 4867584);   // 256*256*2
    float*  cvec  = (float*) (ws + 4998656);   // 256*4

    hipMemsetAsync(flags, 0, 4097 * sizeof(int), stream);

    cn_kernel<<<EE / 4, 256, 0, stream>>>(nbr, tar, xcn, flags);
    table_kernel<<<4097, 256, 0, stream>>>(cn_w1, cn_b1, cn_w2, cn_b2,
                                           cn_w3, cn_b3, beta, lin_w1, flags, T2);
    transpose_w<<<64, 256, 0, stream>>>(ij_w1, Wt1);
    mt_kernel<<<256, 256, 0, stream>>>(ij_w2, lin_w1, Mt);
    cvec_kernel<<<1, 256, 0, stream>>>(ij_b2, lin_w1, lin_b1, cvec);

    fused_kernel<<<EE / 64, 256, 0, stream>>>(x, tar, Wt1, ij_b1, Mt, cvec,
                                              T2, xcn, lin_w2, lin_b2,
                                              (float*)d_out);
}

// Round 3
// 389.579 us; speedup vs baseline: 1.0965x; 1.0843x over previous
//
#include <hip/hip_runtime.h>
#include <hip/hip_bf16.h>
#include <stdint.h>

#define EE 131072
#define DDEG 64

typedef __bf16 bf16_t;
typedef bf16_t bf16x8 __attribute__((ext_vector_type(8)));
typedef float floatx4 __attribute__((ext_vector_type(4)));

// ---------------- CN pair-count: one wave per edge, scalar b-row ----------------
__global__ __launch_bounds__(256)
void cn_kernel(const int* __restrict__ nbr, const int* __restrict__ tar,
               int* __restrict__ xcn, int* __restrict__ flags) {
    int wid  = (blockIdx.x * 256 + threadIdx.x) >> 6;
    int lane = threadIdx.x & 63;
    int s = __builtin_amdgcn_readfirstlane(tar[wid]);
    int d = __builtin_amdgcn_readfirstlane(tar[EE + wid]);
    int a = nbr[(size_t)s * DDEG + lane];                  // coalesced 256B row
    const int* __restrict__ brow = nbr + (size_t)d * DDEG; // uniform -> s_load
    int cnt = 0;
    #pragma unroll
    for (int k = 0; k < 64; ++k) {
        int bk = brow[k];
        cnt += __builtin_popcountll(__ballot(a == bk));
    }
    if (lane == 0) { xcn[wid] = cnt; flags[cnt] = 1; }
}

// ---------------- CN-MLP table folded through lin_w1 ----------------
__global__ __launch_bounds__(256)
void table_kernel(const float* __restrict__ w1, const float* __restrict__ b1,
                  const float* __restrict__ w2, const float* __restrict__ b2,
                  const float* __restrict__ w3, const float* __restrict__ b3,
                  const float* __restrict__ beta, const float* __restrict__ lw1,
                  const int* __restrict__ flags, float* __restrict__ T2) {
    int v = blockIdx.x;
    if (flags[v] == 0) return;    // uniform, before any barrier
    int h = threadIdx.x;
    __shared__ float t1[256];
    __shared__ float t2[256];
    __shared__ float t3[256];
    float fv = (float)v;
    t1[h] = fmaxf(fv * w1[h] + b1[h], 0.f);
    __syncthreads();
    float s = b2[h];
    for (int k = 0; k < 256; ++k) s += t1[k] * w2[k * 256 + h];
    t2[h] = fmaxf(s, 0.f);
    __syncthreads();
    s = b3[h];
    for (int k = 0; k < 256; ++k) s += t2[k] * w3[k * 256 + h];
    t3[h] = s * beta[0];
    __syncthreads();
    s = 0.f;
    for (int k = 0; k < 256; ++k) s += t3[k] * lw1[k * 256 + h];
    T2[(size_t)v * 256 + h] = s;
}

// ---------------- prep: Wt1 transpose | Mt=ij_w2@lin_w1 (bf16 [n][k]) |
//                  cvec=ij_b2@lin_w1+lin_b1 | zero flags --------------------
__global__ __launch_bounds__(256)
void prep_kernel(const float* __restrict__ ij_w1, bf16_t* __restrict__ Wt1,
                 const float* __restrict__ w2, const float* __restrict__ lw1,
                 bf16_t* __restrict__ Mt,
                 const float* __restrict__ b2, const float* __restrict__ lb1,
                 float* __restrict__ cvec, int* __restrict__ flags) {
    __shared__ float tile[32][33];
    __shared__ float S[256][33];
    __shared__ float red[256];
    int bid = blockIdx.x;
    int t = threadIdx.x;
    if (bid < 64) {
        // transpose ij_w1 fp32[k][n] -> bf16 Wt1[n][k]
        int bx = bid & 7, by = bid >> 3;
        int tx = t & 31, ty = t >> 5;
        #pragma unroll
        for (int r = 0; r < 32; r += 8)
            tile[ty + r][tx] = ij_w1[(by * 32 + ty + r) * 256 + bx * 32 + tx];
        __syncthreads();
        #pragma unroll
        for (int r = 0; r < 32; r += 8)
            Wt1[(bx * 32 + ty + r) * 256 + by * 32 + tx] = (bf16_t)tile[tx][ty + r];
    } else if (bid < 320) {
        int b = bid - 64;
        int cc = t & 31, abase = t >> 5;
        float acc = 0.f;
        for (int c0 = 0; c0 < 256; c0 += 32) {
            __syncthreads();
            #pragma unroll
            for (int r = 0; r < 32; ++r) {
                int a = r * 8 + abase;
                S[a][cc] = w2[a * 256 + c0 + cc];
            }
            __syncthreads();
            #pragma unroll 8
            for (int c2 = 0; c2 < 32; ++c2) {
                float wv = lw1[(c0 + c2) * 256 + b];   // uniform -> scalar
                acc += S[t][c2] * wv;
            }
        }
        Mt[(size_t)b * 256 + t] = (bf16_t)acc;
    } else if (bid < 576) {
        int b = bid - 320;
        red[t] = b2[t] * lw1[t * 256 + b];
        __syncthreads();
        for (int s = 128; s > 0; s >>= 1) {
            if (t < s) red[t] += red[t + s];
            __syncthreads();
        }
        if (t == 0) cvec[b] = red[0] + lb1[b];
    } else {
        int i = (bid - 576) * 256 + t;
        if (i < 4097) flags[i] = 0;
    }
}

// ---------------- fused: g=relu((xi*xj)@W1+b1); z=relu(g@M + cvec + T2[xcn]);
//                  out = z@lin_w2 + lin_b2.   64 rows/block, 256 threads. ------
__global__ __launch_bounds__(256, 3)
void fused_kernel(const float* __restrict__ x, const int* __restrict__ tar,
                  const bf16_t* __restrict__ Wt1, const float* __restrict__ b1,
                  const bf16_t* __restrict__ Mt, const float* __restrict__ cvec,
                  const float* __restrict__ T2, const int* __restrict__ xcn,
                  const float* __restrict__ w2, const float* __restrict__ b2s,
                  float* __restrict__ out) {
    // LDS map (54272 B total -> 3 blocks/CU):
    //   [0, 20480)      lB : 256 rows x 32k, pitch 40 bf16
    //   [20480, 54272)  gt : 64 rows x 256k, pitch 264 bf16
    //                   lA : 64 rows x 32k, pitch 40   (aliases gt; dead before gt written)
    //                   rowacc : 64 fp32               (aliases gt; used after gt dead)
    __shared__ __align__(16) char sm[54272];
    bf16_t* const lB     = (bf16_t*)sm;
    bf16_t* const gt     = (bf16_t*)(sm + 20480);
    bf16_t* const lA     = (bf16_t*)(sm + 20480);
    float*  const rowacc = (float*)(sm + 20480);

    const int tid  = threadIdx.x;
    const int lane = tid & 63;
    const int wc   = tid >> 6;          // wave = col quarter 0..3
    const int quad = lane >> 4;
    const int l16  = lane & 15;
    const int e0   = blockIdx.x * 64;

    floatx4 acc[4][4];
    #pragma unroll
    for (int i = 0; i < 4; ++i)
        #pragma unroll
        for (int j = 0; j < 4; ++j)
            acc[i][j] = (floatx4){0.f, 0.f, 0.f, 0.f};

    const int srow  = tid >> 2;          // 0..63, 4 thr/row
    const int skoff = (tid & 3) * 8;
    const int brow  = tid;               // 0..255, 1 thr/row, 32 el

    int e = e0 + srow;
    const float* xi = x + (size_t)tar[e] * 256;
    const float* xj = x + (size_t)tar[EE + e] * 256;
    const bf16_t* w1row = Wt1 + (size_t)brow * 256;

    // ---- GEMM1: (xi*xj) @ W1 ----
    #pragma unroll 1
    for (int kc = 0; kc < 8; ++kc) {
        const int k0 = kc * 32;
        {
            float4 a0 = *(const float4*)(xi + k0 + skoff);
            float4 a1 = *(const float4*)(xi + k0 + skoff + 4);
            float4 c0 = *(const float4*)(xj + k0 + skoff);
            float4 c1 = *(const float4*)(xj + k0 + skoff + 4);
            bf16x8 v;
            v[0] = (bf16_t)(a0.x * c0.x); v[1] = (bf16_t)(a0.y * c0.y);
            v[2] = (bf16_t)(a0.z * c0.z); v[3] = (bf16_t)(a0.w * c0.w);
            v[4] = (bf16_t)(a1.x * c1.x); v[5] = (bf16_t)(a1.y * c1.y);
            v[6] = (bf16_t)(a1.z * c1.z); v[7] = (bf16_t)(a1.w * c1.w);
            *(bf16x8*)&lA[srow * 40 + skoff] = v;
        }
        {
            bf16_t* db = &lB[brow * 40];
            *(bf16x8*)(db)      = *(const bf16x8*)(w1row + k0);
            *(bf16x8*)(db + 8)  = *(const bf16x8*)(w1row + k0 + 8);
            *(bf16x8*)(db + 16) = *(const bf16x8*)(w1row + k0 + 16);
            *(bf16x8*)(db + 24) = *(const bf16x8*)(w1row + k0 + 24);
        }
        __syncthreads();
        bf16x8 af[4], bfr[4];
        const bf16_t* pa = &lA[l16 * 40 + quad * 8];
        const bf16_t* pb = &lB[(wc * 64 + l16) * 40 + quad * 8];
        #pragma unroll
        for (int i = 0; i < 4; ++i) af[i]  = *(const bf16x8*)(pa + i * 16 * 40);
        #pragma unroll
        for (int j = 0; j < 4; ++j) bfr[j] = *(const bf16x8*)(pb + j * 16 * 40);
        #pragma unroll
        for (int i = 0; i < 4; ++i)
            #pragma unroll
            for (int j = 0; j < 4; ++j)
                acc[i][j] = __builtin_amdgcn_mfma_f32_16x16x32_bf16(
                                af[i], bfr[j], acc[i][j], 0, 0, 0);
        __syncthreads();
    }

    // ---- epilogue 1: g tile -> LDS (bf16), clobbers lA region ----
    #pragma unroll
    for (int j = 0; j < 4; ++j) {
        int col  = wc * 64 + j * 16 + l16;
        float bv = b1[col];
        #pragma unroll
        for (int i = 0; i < 4; ++i)
            #pragma unroll
            for (int r = 0; r < 4; ++r) {
                int row = i * 16 + quad * 4 + r;
                gt[row * 264 + col] = (bf16_t)fmaxf(acc[i][j][r] + bv, 0.f);
            }
    }
    #pragma unroll
    for (int i = 0; i < 4; ++i)
        #pragma unroll
        for (int j = 0; j < 4; ++j)
            acc[i][j] = (floatx4){0.f, 0.f, 0.f, 0.f};
    __syncthreads();

    // ---- GEMM2': g @ M ----
    const bf16_t* mrow = Mt + (size_t)brow * 256;
    #pragma unroll 1
    for (int kc = 0; kc < 8; ++kc) {
        const int k0 = kc * 32;
        {
            bf16_t* db = &lB[brow * 40];
            *(bf16x8*)(db)      = *(const bf16x8*)(mrow + k0);
            *(bf16x8*)(db + 8)  = *(const bf16x8*)(mrow + k0 + 8);
            *(bf16x8*)(db + 16) = *(const bf16x8*)(mrow + k0 + 16);
            *(bf16x8*)(db + 24) = *(const bf16x8*)(mrow + k0 + 24);
        }
        __syncthreads();
        bf16x8 af[4], bfr[4];
        const bf16_t* pa = &gt[l16 * 264 + k0 + quad * 8];
        const bf16_t* pb = &lB[(wc * 64 + l16) * 40 + quad * 8];
        #pragma unroll
        for (int i = 0; i < 4; ++i) af[i]  = *(const bf16x8*)(pa + i * 16 * 264);
        #pragma unroll
        for (int j = 0; j < 4; ++j) bfr[j] = *(const bf16x8*)(pb + j * 16 * 40);
        #pragma unroll
        for (int i = 0; i < 4; ++i)
            #pragma unroll
            for (int j = 0; j < 4; ++j)
                acc[i][j] = __builtin_amdgcn_mfma_f32_16x16x32_bf16(
                                af[i], bfr[j], acc[i][j], 0, 0, 0);
        __syncthreads();
    }
    // gt is dead from here; rowacc aliases it.
    if (tid < 64) rowacc[tid] = 0.f;

    // ---- final epilogue: +cvec +T2[xcn], relu, dot lin_w2, row-reduce ----
    int xv[16];
    #pragma unroll
    for (int i = 0; i < 4; ++i)
        #pragma unroll
        for (int r = 0; r < 4; ++r)
            xv[i * 4 + r] = xcn[e0 + i * 16 + quad * 4 + r];

    float pr[16];
    #pragma unroll
    for (int t = 0; t < 16; ++t) pr[t] = 0.f;
    #pragma unroll
    for (int j = 0; j < 4; ++j) {
        int col  = wc * 64 + j * 16 + l16;
        float cv = cvec[col];
        float wv = w2[col];
        #pragma unroll
        for (int i = 0; i < 4; ++i)
            #pragma unroll
            for (int r = 0; r < 4; ++r) {
                float t2v = T2[(size_t)xv[i * 4 + r] * 256 + col];
                float v = fmaxf(acc[i][j][r] + cv + t2v, 0.f);
                pr[i * 4 + r] += v * wv;
            }
    }
    #pragma unroll
    for (int off = 1; off < 16; off <<= 1)
        #pragma unroll
        for (int t = 0; t < 16; ++t)
            pr[t] += __shfl_xor(pr[t], off, 64);
    __syncthreads();   // rowacc init visible before atomics
    if (l16 == 0) {
        #pragma unroll
        for (int i = 0; i < 4; ++i)
            #pragma unroll
            for (int r = 0; r < 4; ++r)
                atomicAdd(&rowacc[i * 16 + quad * 4 + r], pr[i * 4 + r]);
    }
    __syncthreads();
    if (tid < 64) out[e0 + tid] = rowacc[tid] + b2s[0];
}

extern "C" void kernel_launch(void* const* d_in, const int* in_sizes, int n_in,
                              void* d_out, int out_size, void* d_ws, size_t ws_size,
                              hipStream_t stream) {
    const float* x      = (const float*)d_in[0];
    const int*   nbr    = (const int*)  d_in[1];
    const int*   tar    = (const int*)  d_in[2];
    const float* beta   = (const float*)d_in[3];
    const float* cn_w1  = (const float*)d_in[4];
    const float* cn_b1  = (const float*)d_in[5];
    const float* cn_w2  = (const float*)d_in[6];
    const float* cn_b2  = (const float*)d_in[7];
    const float* cn_w3  = (const float*)d_in[8];
    const float* cn_b3  = (const float*)d_in[9];
    const float* ij_w1  = (const float*)d_in[10];
    const float* ij_b1  = (const float*)d_in[11];
    const float* ij_w2  = (const float*)d_in[12];
    const float* ij_b2  = (const float*)d_in[13];
    const float* lin_w1 = (const float*)d_in[14];
    const float* lin_b1 = (const float*)d_in[15];
    const float* lin_w2 = (const float*)d_in[16];
    const float* lin_b2 = (const float*)d_in[17];

    char* ws = (char*)d_ws;
    float*  T2    = (float*) (ws + 0);         // 4097*256*4 = 4,195,328
    int*    flags = (int*)   (ws + 4195328);   // 4097*4
    int*    xcn   = (int*)   (ws + 4212224);   // E*4
    bf16_t* Wt1   = (bf16_t*)(ws + 4736512);   // 256*256*2
    bf16_t* Mt    = (bf16_t*)(ws + 4867584);   // 256*256*2
    float*  cvec  = (float*) (ws + 4998656);   // 256*4

    prep_kernel<<<593, 256, 0, stream>>>(ij_w1, Wt1, ij_w2, lin_w1, Mt,
                                         ij_b2, lin_b1, cvec, flags);
    cn_kernel<<<EE / 4, 256, 0, stream>>>(nbr, tar, xcn, flags);
    table_kernel<<<4097, 256, 0, stream>>>(cn_w1, cn_b1, cn_w2, cn_b2,
                                           cn_w3, cn_b3, beta, lin_w1, flags, T2);
    fused_kernel<<<EE / 64, 256, 0, stream>>>(x, tar, Wt1, ij_b1, Mt, cvec,
                                              T2, xcn, lin_w2, lin_b2,
                                              (float*)d_out);
}